// Round 7
// baseline (244.284 us; speedup 1.0000x reference)
//
#include <hip/hip_runtime.h>
#include <hip/hip_bf16.h>

typedef unsigned short u16;
typedef __bf16 bf16x8 __attribute__((ext_vector_type(8)));
typedef float f32x4 __attribute__((ext_vector_type(4)));

#define MARGIN 0.2f
#define NEG_INF -3.0e38f

__device__ __forceinline__ u16 f2bf_rne(float f) {
  unsigned u = __builtin_bit_cast(unsigned, f);
  u += 0x7FFFu + ((u >> 16) & 1u);
  return (u16)(u >> 16);
}

// ---------------- prep: fp32 -> bf16 + row sum-of-squares (+ fused zero/cvt) ---
__global__ void prep_kernel(const float* __restrict__ A, const float* __restrict__ P,
                            const float* __restrict__ Ng, const int* __restrict__ tg,
                            u16* __restrict__ Ab, u16* __restrict__ Pb, u16* __restrict__ Nb,
                            float* __restrict__ an, float* __restrict__ pn, float* __restrict__ nn,
                            int* __restrict__ cls, float* __restrict__ out, int D, int N) {
  if (blockIdx.y == 0) {
    if (blockIdx.x == 0 && threadIdx.x == 0) out[0] = 0.f;
    if ((int)blockIdx.x < (N >> 8)) {
      const int i = blockIdx.x * 256 + threadIdx.x;
      cls[i] = tg[i];
    }
  }
  const int row  = blockIdx.x * 4 + (threadIdx.x >> 6);
  const int lane = threadIdx.x & 63;
  const float* src; u16* dst; float* nrm;
  if (blockIdx.y == 0)      { src = A;  dst = Ab; nrm = an; }
  else if (blockIdx.y == 1) { src = P;  dst = Pb; nrm = pn; }
  else                      { src = Ng; dst = Nb; nrm = nn; }
  float4 v = *(const float4*)(src + (size_t)row * D + lane * 4);
  float ss = v.x * v.x + v.y * v.y + v.z * v.z + v.w * v.w;
  ushort4 o = make_ushort4(f2bf_rne(v.x), f2bf_rne(v.y), f2bf_rne(v.z), f2bf_rne(v.w));
  *(ushort4*)(dst + (size_t)row * D + lane * 4) = o;
  #pragma unroll
  for (int m = 1; m < 64; m <<= 1) ss += __shfl_xor(ss, m);
  if (lane == 0) nrm[row] = ss;
}

// ---------------- staging: 128 rows x 64 bf16 of g[rbase..][kb*64..] -> LDS -----
// LDS dest linear (required by global_load_lds); XOR read-swizzle realized by
// pre-swizzling the per-lane GLOBAL source (both-sides-or-neither pairing).
__device__ __forceinline__ void stage_tile(const u16* __restrict__ g, u16* lds,
                                           int rbase, int kb, int D, int w, int l) {
  #pragma unroll
  for (int c = 0; c < 4; ++c) {
    const int row  = w * 32 + c * 8 + (l >> 3);   // 8 lanes cover one 128B row
    const int slot = (l & 7) ^ (row & 7);         // inverse of read-side swizzle
    const u16* gp = g + (size_t)(rbase + row) * D + kb * 64 + slot * 8;
    u16* lp = lds + w * 2048 + c * 512;           // wave-uniform base; HW adds lane*16B
    __builtin_amdgcn_global_load_lds((const __attribute__((address_space(1))) void*)gp,
                                     (__attribute__((address_space(3))) void*)lp,
                                     16, 0, 0);
  }
}

// ---------------- main fused kernel -------------------------------------------
// z-split: z=0 -> A·P^T masked row-max; z=1 -> A·N^T masked row-min (-max(-x)).
// 128x128 tile, 4 waves (2x2), K=256 in 4 K-tiles of 64.
// 2-phase prefetch pipeline (T3-minimum): STAGE(t+1) issued BEFORE compute(t);
// single vmcnt(0)+barrier per K-tile AFTER compute -> stage latency hidden.
__global__ __launch_bounds__(256, 2) void triplet_tile_kernel(
    const u16* __restrict__ Ab, const u16* __restrict__ Pb, const u16* __restrict__ Nb,
    const float* __restrict__ pnorm, const float* __restrict__ nnorm,
    const int* __restrict__ cls,
    float* __restrict__ maxP, float* __restrict__ minN, int N, int D) {
  __shared__ __align__(16) u16 As[2][128 * 64];   // 2 x 16 KB
  __shared__ __align__(16) u16 Bs[2][128 * 64];   // 2 x 16 KB
  __shared__ float nS[128];
  __shared__ int   ccS[128], rcS[128];
  __shared__ float red[2][128];

  const int cb = blockIdx.x, rb = blockIdx.y, z = blockIdx.z;
  const int rowbase = rb * 128, colbase = cb * 128;
  const u16*  __restrict__ Bmat = z ? Nb : Pb;
  const float* __restrict__ cn  = z ? nnorm : pnorm;
  const float sgn = z ? -1.f : 1.f;

  const int t = threadIdx.x, l = t & 63, w = t >> 6;
  const int wr = w >> 1, wc = w & 1, g = l >> 4, lr = l & 15;

  if (t < 128) {
    nS[t]  = cn[colbase + t];
    ccS[t] = cls[colbase + t];
  } else {
    rcS[t - 128] = cls[rowbase + (t - 128)];
  }

  f32x4 acc[4][4];
  #pragma unroll
  for (int m = 0; m < 4; ++m)
    #pragma unroll
    for (int n = 0; n < 4; ++n) acc[m][n] = (f32x4){0.f, 0.f, 0.f, 0.f};

  // prologue: stage K-tile 0, drain, sync
  stage_tile(Ab,   As[0], rowbase, 0, D, w, l);
  stage_tile(Bmat, Bs[0], colbase, 0, D, w, l);
  asm volatile("s_waitcnt vmcnt(0)" ::: "memory");
  __builtin_amdgcn_s_barrier();

  const int nKB = D / 64;                  // 4
  for (int kb = 0; kb < nKB; ++kb) {
    const int cur = kb & 1;
    // issue next tile's stage FIRST (targets buf[cur^1], last read in kb-1,
    // protected by end-of-previous-iteration barrier)
    if (kb + 1 < nKB) {
      stage_tile(Ab,   As[cur ^ 1], rowbase, kb + 1, D, w, l);
      stage_tile(Bmat, Bs[cur ^ 1], colbase, kb + 1, D, w, l);
    }
    // compute current tile (ds_read + MFMA; ~400+ cyc hides the stage above)
    const u16* __restrict__ Ac = As[cur];
    const u16* __restrict__ Bc = Bs[cur];
    #pragma unroll
    for (int kk = 0; kk < 2; ++kk) {
      bf16x8 af[4], bf[4];
      #pragma unroll
      for (int m = 0; m < 4; ++m) {
        const int row  = wr * 64 + m * 16 + lr;
        const int slot = (kk * 4 + g) ^ (row & 7);
        af[m] = *(const bf16x8*)&Ac[row * 64 + slot * 8];
      }
      #pragma unroll
      for (int n = 0; n < 4; ++n) {
        const int col  = wc * 64 + n * 16 + lr;
        const int slot = (kk * 4 + g) ^ (col & 7);
        bf[n] = *(const bf16x8*)&Bc[col * 64 + slot * 8];
      }
      #pragma unroll
      for (int m = 0; m < 4; ++m)
        #pragma unroll
        for (int n = 0; n < 4; ++n)
          acc[m][n] = __builtin_amdgcn_mfma_f32_16x16x32_bf16(af[m], bf[n], acc[m][n], 0, 0, 0);
    }
    // close the tile: next-tile loads (issued ~400 cyc ago) drain cheaply;
    // barrier also protects buf[cur] reads vs kb+1's stage into buf[cur^1... cur]
    if (kb + 1 < nKB) {
      asm volatile("s_waitcnt vmcnt(0)" ::: "memory");
      __builtin_amdgcn_s_barrier();
    }
  }

  // Epilogue: masked row reduce on sgn*(colnorm - 2*dot); C/D layout:
  // col = lane&15, row = (lane>>4)*4 + reg  [measured m89/m91]
  #pragma unroll
  for (int m = 0; m < 4; ++m) {
    #pragma unroll
    for (int r = 0; r < 4; ++r) {
      const int row = wr * 64 + m * 16 + g * 4 + r;
      const int rc  = rcS[row];
      float v = NEG_INF;
      #pragma unroll
      for (int n = 0; n < 4; ++n) {
        const int col = wc * 64 + n * 16 + lr;
        const bool same = (rc == ccS[col]);
        const bool want = z ? !same : same;
        const float q = sgn * fmaf(-2.f, acc[m][n][r], nS[col]);
        v = want ? fmaxf(v, q) : v;
      }
      #pragma unroll
      for (int msk = 1; msk < 16; msk <<= 1) v = fmaxf(v, __shfl_xor(v, msk));
      if (lr == 0) red[wc][row] = v;
    }
  }
  __syncthreads();
  if (t < 128) {
    const float v = fmaxf(red[0][t], red[1][t]);
    float* __restrict__ outp = z ? minN : maxP;
    outp[(size_t)cb * N + rowbase + t] = sgn * v;   // z=1: -max(-x) = min(x)
  }
}

// ---------------- finalize: combine partials, loss, mean ----------------------
__global__ void finalize_kernel(const float* __restrict__ maxP, const float* __restrict__ minN,
                                const float* __restrict__ an, float* out, int N, int nCB) {
  const int r = blockIdx.x * 128 + threadIdx.x;
  float mx = NEG_INF, mn = 3.0e38f;
  for (int cb = 0; cb < nCB; ++cb) {
    mx = fmaxf(mx, maxP[(size_t)cb * N + r]);
    mn = fminf(mn, minN[(size_t)cb * N + r]);
  }
  const float a  = an[r];
  const float dp = sqrtf(fmaxf(a + mx, 1e-12f));
  const float dn = sqrtf(fmaxf(a + mn, 1e-12f));
  float loss = fmaxf(dp - dn + MARGIN, 0.f);
  #pragma unroll
  for (int msk = 1; msk < 64; msk <<= 1) loss += __shfl_xor(loss, msk);
  __shared__ float s[2];
  if ((threadIdx.x & 63) == 0) s[threadIdx.x >> 6] = loss;
  __syncthreads();
  if (threadIdx.x == 0) atomicAdd(out, (s[0] + s[1]) * (1.0f / N));
}

extern "C" void kernel_launch(void* const* d_in, const int* in_sizes, int n_in,
                              void* d_out, int out_size, void* d_ws, size_t ws_size,
                              hipStream_t stream) {
  const float* A  = (const float*)d_in[0];
  const float* P  = (const float*)d_in[1];
  const float* Ng = (const float*)d_in[2];
  const int*   tg = (const int*)d_in[3];
  float* out = (float*)d_out;

  const int N = in_sizes[3];        // 8192
  const int D = in_sizes[0] / N;    // 256
  const int nRB = N / 128, nCB = N / 128;

  char* ws = (char*)d_ws;
  const size_t bf = (size_t)N * D * sizeof(u16);
  u16* Ab = (u16*)ws;
  u16* Pb = (u16*)(ws + bf);
  u16* Nb = (u16*)(ws + 2 * bf);
  char* p = ws + 3 * bf;
  float* an = (float*)p; p += (size_t)N * 4;
  float* pn = (float*)p; p += (size_t)N * 4;
  float* nn = (float*)p; p += (size_t)N * 4;
  int*  cls = (int*)p;   p += (size_t)N * 4;
  float* maxP = (float*)p; p += (size_t)nCB * N * 4;
  float* minN = (float*)p;

  prep_kernel<<<dim3(N / 4, 3), 256, 0, stream>>>(A, P, Ng, tg, Ab, Pb, Nb,
                                                  an, pn, nn, cls, out, D, N);
  triplet_tile_kernel<<<dim3(nCB, nRB, 2), 256, 0, stream>>>(Ab, Pb, Nb, pn, nn, cls,
                                                             maxP, minN, N, D);
  finalize_kernel<<<N / 128, 128, 0, stream>>>(maxP, minN, an, out, N, nCB);
}

// Round 9
// 176.900 us; speedup vs baseline: 1.3809x; 1.3809x over previous
//
#include <hip/hip_runtime.h>
#include <hip/hip_bf16.h>

typedef unsigned short u16;
typedef __bf16 bf16x8 __attribute__((ext_vector_type(8)));
typedef float f32x4 __attribute__((ext_vector_type(4)));

#define MARGIN 0.2f
#define NEG_INF -3.0e38f

__device__ __forceinline__ u16 f2bf_rne(float f) {
  unsigned u = __builtin_bit_cast(unsigned, f);
  u += 0x7FFFu + ((u >> 16) & 1u);
  return (u16)(u >> 16);
}

// ---------------- prep: fp32 -> bf16 + row sum-of-squares (+ fused zero/cvt) ---
__global__ void prep_kernel(const float* __restrict__ A, const float* __restrict__ P,
                            const float* __restrict__ Ng, const int* __restrict__ tg,
                            u16* __restrict__ Ab, u16* __restrict__ Pb, u16* __restrict__ Nb,
                            float* __restrict__ an, float* __restrict__ pn, float* __restrict__ nn,
                            int* __restrict__ cls, float* __restrict__ out, int D, int N) {
  if (blockIdx.y == 0) {
    if (blockIdx.x == 0 && threadIdx.x == 0) out[0] = 0.f;
    if ((int)blockIdx.x < (N >> 8)) {
      const int i = blockIdx.x * 256 + threadIdx.x;
      cls[i] = tg[i];
    }
  }
  const int row  = blockIdx.x * 4 + (threadIdx.x >> 6);
  const int lane = threadIdx.x & 63;
  const float* src; u16* dst; float* nrm;
  if (blockIdx.y == 0)      { src = A;  dst = Ab; nrm = an; }
  else if (blockIdx.y == 1) { src = P;  dst = Pb; nrm = pn; }
  else                      { src = Ng; dst = Nb; nrm = nn; }
  float4 v = *(const float4*)(src + (size_t)row * D + lane * 4);
  float ss = v.x * v.x + v.y * v.y + v.z * v.z + v.w * v.w;
  ushort4 o = make_ushort4(f2bf_rne(v.x), f2bf_rne(v.y), f2bf_rne(v.z), f2bf_rne(v.w));
  *(ushort4*)(dst + (size_t)row * D + lane * 4) = o;
  #pragma unroll
  for (int m = 1; m < 64; m <<= 1) ss += __shfl_xor(ss, m);
  if (lane == 0) nrm[row] = ss;
}

// ---------------- staging: 128 rows x 64 bf16 of g[rbase..][kb*64..] -> LDS -----
// LDS dest linear (required by global_load_lds); XOR read-swizzle realized by
// pre-swizzling the per-lane GLOBAL source (both-sides-or-neither pairing).
__device__ __forceinline__ void stage_tile(const u16* __restrict__ g, u16* lds,
                                           int rbase, int kb, int D, int w, int l) {
  #pragma unroll
  for (int c = 0; c < 4; ++c) {
    const int row  = w * 32 + c * 8 + (l >> 3);   // 8 lanes cover one 128B row
    const int slot = (l & 7) ^ (row & 7);         // inverse of read-side swizzle
    const u16* gp = g + (size_t)(rbase + row) * D + kb * 64 + slot * 8;
    u16* lp = lds + w * 2048 + c * 512;           // wave-uniform base; HW adds lane*16B
    __builtin_amdgcn_global_load_lds((const __attribute__((address_space(1))) void*)gp,
                                     (__attribute__((address_space(3))) void*)lp,
                                     16, 0, 0);
  }
}

// ---------------- main fused kernel -------------------------------------------
// z-split: z=0 -> A·P^T masked row-max; z=1 -> A·N^T masked row-min (-max(-x)).
// 128x128 tile, 4 waves (2x2), K=256 in 4 K-tiles of 64. Single-buffered,
// 2 barriers/K-tile, 4 blocks/CU (R6 structure — frozen).
// CHANGE vs R6: ds_read addresses reduced to 2 base regs + immediate offsets
// (addr(m,kk) = base ^ (kk*64) + m*2048) — kills per-iteration VALU remat.
__global__ __launch_bounds__(256, 4) void triplet_tile_kernel(
    const u16* __restrict__ Ab, const u16* __restrict__ Pb, const u16* __restrict__ Nb,
    const float* __restrict__ pnorm, const float* __restrict__ nnorm,
    const int* __restrict__ cls,
    float* __restrict__ maxP, float* __restrict__ minN, int N, int D, int nCB) {
  __shared__ __align__(16) u16 As[128 * 64];      // 16 KB
  __shared__ __align__(16) u16 Bs[128 * 64];      // 16 KB
  __shared__ float nS[128];
  __shared__ int   ccS[128], rcS[128];
  __shared__ float red[2][128];

  const int cb = blockIdx.x, rb = blockIdx.y, z = blockIdx.z;
  const int rowbase = rb * 128, colbase = cb * 128;
  const u16*  __restrict__ Bmat = z ? Nb : Pb;
  const float* __restrict__ cn  = z ? nnorm : pnorm;
  const float sgn = z ? -1.f : 1.f;

  const int t = threadIdx.x, l = t & 63, w = t >> 6;
  const int wr = w >> 1, wc = w & 1, g = l >> 4, lr = l & 15;

  if (t < 128) {
    nS[t]  = cn[colbase + t];
    ccS[t] = cls[colbase + t];
  } else {
    rcS[t - 128] = cls[rowbase + (t - 128)];
  }

  // Loop-invariant swizzled LDS byte addresses:
  // row&7 == l&7 for all fragments -> slot0 = g ^ (l&7) lane-constant.
  // A read (m,kk): (abase ^ kk*64) + m*2048 ; B read (n,kk): (bbase ^ kk*64) + n*2048
  const int swz   = ((l >> 4) ^ (l & 7)) * 16;
  const int abase = (wr * 64 + lr) * 128 + swz;
  const int bbase = (wc * 64 + lr) * 128 + swz;
  const char* __restrict__ Ac = (const char*)As;
  const char* __restrict__ Bc = (const char*)Bs;

  f32x4 acc[4][4];
  #pragma unroll
  for (int m = 0; m < 4; ++m)
    #pragma unroll
    for (int n = 0; n < 4; ++n) acc[m][n] = (f32x4){0.f, 0.f, 0.f, 0.f};

  const int nKB = D / 64;
  for (int kb = 0; kb < nKB; ++kb) {
    __syncthreads();                       // previous tile fully consumed
    stage_tile(Ab,   As, rowbase, kb, D, w, l);
    stage_tile(Bmat, Bs, colbase, kb, D, w, l);
    __syncthreads();                       // drains vmcnt -> LDS data visible
    #pragma unroll
    for (int kk = 0; kk < 2; ++kk) {
      const int sel = kk * 64;
      bf16x8 af[4], bf[4];
      #pragma unroll
      for (int m = 0; m < 4; ++m)
        af[m] = *(const bf16x8*)(Ac + ((abase ^ sel) + m * 2048));
      #pragma unroll
      for (int n = 0; n < 4; ++n)
        bf[n] = *(const bf16x8*)(Bc + ((bbase ^ sel) + n * 2048));
      #pragma unroll
      for (int m = 0; m < 4; ++m)
        #pragma unroll
        for (int n = 0; n < 4; ++n)
          acc[m][n] = __builtin_amdgcn_mfma_f32_16x16x32_bf16(af[m], bf[n], acc[m][n], 0, 0, 0);
    }
  }

  // Epilogue: masked row reduce on sgn*(colnorm - 2*dot); C/D layout:
  // col = lane&15, row = (lane>>4)*4 + reg  [measured m89/m91]
  #pragma unroll
  for (int m = 0; m < 4; ++m) {
    #pragma unroll
    for (int r = 0; r < 4; ++r) {
      const int row = wr * 64 + m * 16 + g * 4 + r;
      const int rc  = rcS[row];
      float v = NEG_INF;
      #pragma unroll
      for (int n = 0; n < 4; ++n) {
        const int col = wc * 64 + n * 16 + lr;
        const bool same = (rc == ccS[col]);
        const bool want = z ? !same : same;
        const float q = sgn * fmaf(-2.f, acc[m][n][r], nS[col]);
        v = want ? fmaxf(v, q) : v;
      }
      #pragma unroll
      for (int msk = 1; msk < 16; msk <<= 1) v = fmaxf(v, __shfl_xor(v, msk));
      if (lr == 0) red[wc][row] = v;
    }
  }
  __syncthreads();
  if (t < 128) {
    const float v = fmaxf(red[0][t], red[1][t]);
    float* __restrict__ outp = z ? minN : maxP;
    // transposed partial layout [row][cb] -> coalesced float4 reads in finalize
    outp[(size_t)(rowbase + t) * nCB + cb] = sgn * v;   // z=1: -max(-x) = min(x)
  }
}

// ---------------- finalize: combine partials, loss, mean ----------------------
__global__ void finalize_kernel(const float* __restrict__ maxP, const float* __restrict__ minN,
                                const float* __restrict__ an, float* out, int N, int nCB) {
  const int r = blockIdx.x * 256 + threadIdx.x;
  const float4* __restrict__ mp = (const float4*)(maxP + (size_t)r * nCB);
  const float4* __restrict__ np = (const float4*)(minN + (size_t)r * nCB);
  float mx = NEG_INF, mn = 3.0e38f;
  for (int i = 0; i < (nCB >> 2); ++i) {
    const float4 a = mp[i];
    mx = fmaxf(mx, fmaxf(fmaxf(a.x, a.y), fmaxf(a.z, a.w)));
    const float4 b = np[i];
    mn = fminf(mn, fminf(fminf(b.x, b.y), fminf(b.z, b.w)));
  }
  const float aa = an[r];
  const float dp = sqrtf(fmaxf(aa + mx, 1e-12f));
  const float dn = sqrtf(fmaxf(aa + mn, 1e-12f));
  float loss = fmaxf(dp - dn + MARGIN, 0.f);
  #pragma unroll
  for (int msk = 1; msk < 64; msk <<= 1) loss += __shfl_xor(loss, msk);
  __shared__ float s[4];
  if ((threadIdx.x & 63) == 0) s[threadIdx.x >> 6] = loss;
  __syncthreads();
  if (threadIdx.x == 0)
    atomicAdd(out, (s[0] + s[1] + s[2] + s[3]) * (1.0f / N));
}

extern "C" void kernel_launch(void* const* d_in, const int* in_sizes, int n_in,
                              void* d_out, int out_size, void* d_ws, size_t ws_size,
                              hipStream_t stream) {
  const float* A  = (const float*)d_in[0];
  const float* P  = (const float*)d_in[1];
  const float* Ng = (const float*)d_in[2];
  const int*   tg = (const int*)d_in[3];
  float* out = (float*)d_out;

  const int N = in_sizes[3];        // 8192
  const int D = in_sizes[0] / N;    // 256
  const int nRB = N / 128, nCB = N / 128;

  char* ws = (char*)d_ws;
  const size_t bf = (size_t)N * D * sizeof(u16);
  u16* Ab = (u16*)ws;
  u16* Pb = (u16*)(ws + bf);
  u16* Nb = (u16*)(ws + 2 * bf);
  char* p = ws + 3 * bf;
  float* an = (float*)p; p += (size_t)N * 4;
  float* pn = (float*)p; p += (size_t)N * 4;
  float* nn = (float*)p; p += (size_t)N * 4;
  int*  cls = (int*)p;   p += (size_t)N * 4;
  float* maxP = (float*)p; p += (size_t)nCB * N * 4;
  float* minN = (float*)p;

  prep_kernel<<<dim3(N / 4, 3), 256, 0, stream>>>(A, P, Ng, tg, Ab, Pb, Nb,
                                                  an, pn, nn, cls, out, D, N);
  triplet_tile_kernel<<<dim3(nCB, nRB, 2), 256, 0, stream>>>(Ab, Pb, Nb, pn, nn, cls,
                                                             maxP, minN, N, D, nCB);
  finalize_kernel<<<N / 256, 256, 0, stream>>>(maxP, minN, an, out, N, nCB);
}

// Round 10
// 163.122 us; speedup vs baseline: 1.4976x; 1.0845x over previous
//
#include <hip/hip_runtime.h>
#include <hip/hip_bf16.h>

typedef unsigned short u16;
typedef __bf16 bf16x8 __attribute__((ext_vector_type(8)));
typedef float f32x4 __attribute__((ext_vector_type(4)));

#define MARGIN 0.2f
#define NEG_INF -3.0e38f

__device__ __forceinline__ u16 f2bf_rne(float f) {
  unsigned u = __builtin_bit_cast(unsigned, f);
  u += 0x7FFFu + ((u >> 16) & 1u);
  return (u16)(u >> 16);
}

// ---------------- prep: fp32 -> bf16 + row sum-of-squares (+ fused zero/cvt) ---
__global__ void prep_kernel(const float* __restrict__ A, const float* __restrict__ P,
                            const float* __restrict__ Ng, const int* __restrict__ tg,
                            u16* __restrict__ Ab, u16* __restrict__ Pb, u16* __restrict__ Nb,
                            float* __restrict__ an, float* __restrict__ pn, float* __restrict__ nn,
                            int* __restrict__ cls, float* __restrict__ out, int D, int N) {
  if (blockIdx.y == 0) {
    if (blockIdx.x == 0 && threadIdx.x == 0) out[0] = 0.f;
    if ((int)blockIdx.x < (N >> 8)) {
      const int i = blockIdx.x * 256 + threadIdx.x;
      cls[i] = tg[i];
    }
  }
  const int row  = blockIdx.x * 4 + (threadIdx.x >> 6);
  const int lane = threadIdx.x & 63;
  const float* src; u16* dst; float* nrm;
  if (blockIdx.y == 0)      { src = A;  dst = Ab; nrm = an; }
  else if (blockIdx.y == 1) { src = P;  dst = Pb; nrm = pn; }
  else                      { src = Ng; dst = Nb; nrm = nn; }
  float4 v = *(const float4*)(src + (size_t)row * D + lane * 4);
  float ss = v.x * v.x + v.y * v.y + v.z * v.z + v.w * v.w;
  ushort4 o = make_ushort4(f2bf_rne(v.x), f2bf_rne(v.y), f2bf_rne(v.z), f2bf_rne(v.w));
  *(ushort4*)(dst + (size_t)row * D + lane * 4) = o;
  #pragma unroll
  for (int m = 1; m < 64; m <<= 1) ss += __shfl_xor(ss, m);
  if (lane == 0) nrm[row] = ss;
}

// ---------------- staging: 128 rows x 64 bf16 of g[rbase..][kb*64..] -> LDS -----
// LDS dest linear (required by global_load_lds); XOR read-swizzle realized by
// pre-swizzling the per-lane GLOBAL source (both-sides-or-neither pairing).
__device__ __forceinline__ void stage_tile(const u16* __restrict__ g, u16* lds,
                                           int rbase, int kb, int D, int w, int l) {
  #pragma unroll
  for (int c = 0; c < 4; ++c) {
    const int row  = w * 32 + c * 8 + (l >> 3);   // 8 lanes cover one 128B row
    const int slot = (l & 7) ^ (row & 7);         // inverse of read-side swizzle
    const u16* gp = g + (size_t)(rbase + row) * D + kb * 64 + slot * 8;
    u16* lp = lds + w * 2048 + c * 512;           // wave-uniform base; HW adds lane*16B
    __builtin_amdgcn_global_load_lds((const __attribute__((address_space(1))) void*)gp,
                                     (__attribute__((address_space(3))) void*)lp,
                                     16, 0, 0);
  }
}

// ---------------- main fused kernel -------------------------------------------
// z-split: z=0 -> masked row-max of (|p_j|^2 - 2 a_i.p_j); z=1 -> row-min via -max.
// 128x128 tile, 4 waves (2x2), K=256 in 4 K-tiles of 64, 4 blocks/CU (frozen).
// CHANGE vs R9: TRANSPOSED MFMA (swap operand order) -> A-rows in lanes,
// P/N-cols in regs. Masked col-reduce becomes in-register (16 ops) + 2 shfl
// instead of 4x16 shfl. Epilogue DS-pipe traffic /8.
__global__ __launch_bounds__(256, 4) void triplet_tile_kernel(
    const u16* __restrict__ Ab, const u16* __restrict__ Pb, const u16* __restrict__ Nb,
    const float* __restrict__ pnorm, const float* __restrict__ nnorm,
    const int* __restrict__ cls,
    float* __restrict__ maxP, float* __restrict__ minN, int N, int D, int nCB) {
  __shared__ __align__(16) u16 As[128 * 64];      // 16 KB
  __shared__ __align__(16) u16 Bs[128 * 64];      // 16 KB
  __shared__ float nS[128];
  __shared__ int   ccS[128], rcS[128];
  __shared__ float red[2][128];

  const int cb = blockIdx.x, rb = blockIdx.y, z = blockIdx.z;
  const int rowbase = rb * 128, colbase = cb * 128;
  const u16*  __restrict__ Bmat = z ? Nb : Pb;
  const float* __restrict__ cn  = z ? nnorm : pnorm;
  const float sgn = z ? -1.f : 1.f;

  const int t = threadIdx.x, l = t & 63, w = t >> 6;
  // wave (wa, wb): wa = C-col half (P/N rows), wb = C-row half (A rows)
  const int wa = w >> 1, wb = w & 1, g = l >> 4, lr = l & 15;

  if (t < 128) {
    nS[t]  = cn[colbase + t];
    ccS[t] = cls[colbase + t];
  } else {
    rcS[t - 128] = cls[rowbase + (t - 128)];
  }

  // Loop-invariant swizzled LDS byte addresses (row&7 == l&7 for all frags):
  // A read (rj,kk): (abase ^ kk*64) + rj*2048 ; B read (ci,kk): (bbase ^ kk*64) + ci*2048
  const int swz   = ((l >> 4) ^ (l & 7)) * 16;
  const int abase = (wb * 64 + lr) * 128 + swz;
  const int bbase = (wa * 64 + lr) * 128 + swz;
  const char* __restrict__ Ac = (const char*)As;
  const char* __restrict__ Bc = (const char*)Bs;

  // acc[ci][rj]: C^T fragment; col i = wa*64+ci*16+g*4+reg (regs),
  //              row j = wb*64+rj*16+lr (lanes)
  f32x4 acc[4][4];
  #pragma unroll
  for (int ci = 0; ci < 4; ++ci)
    #pragma unroll
    for (int rj = 0; rj < 4; ++rj) acc[ci][rj] = (f32x4){0.f, 0.f, 0.f, 0.f};

  const int nKB = D / 64;
  for (int kb = 0; kb < nKB; ++kb) {
    __syncthreads();                       // previous tile fully consumed
    stage_tile(Ab,   As, rowbase, kb, D, w, l);
    stage_tile(Bmat, Bs, colbase, kb, D, w, l);
    __syncthreads();                       // drains vmcnt -> LDS data visible
    #pragma unroll
    for (int kk = 0; kk < 2; ++kk) {
      const int sel = kk * 64;
      bf16x8 af[4], bf[4];
      #pragma unroll
      for (int rj = 0; rj < 4; ++rj)
        af[rj] = *(const bf16x8*)(Ac + ((abase ^ sel) + rj * 2048));
      #pragma unroll
      for (int ci = 0; ci < 4; ++ci)
        bf[ci] = *(const bf16x8*)(Bc + ((bbase ^ sel) + ci * 2048));
      // swapped operands: D = (P/N-frag) x (A-frag) -> transposed tile
      #pragma unroll
      for (int ci = 0; ci < 4; ++ci)
        #pragma unroll
        for (int rj = 0; rj < 4; ++rj)
          acc[ci][rj] = __builtin_amdgcn_mfma_f32_16x16x32_bf16(bf[ci], af[rj], acc[ci][rj], 0, 0, 0);
    }
  }

  // ---- epilogue: masked reduce, cols in registers ----
  // q = sgn*(colnorm - 2*dot) = fmaf(-2*sgn, dot, sgn*colnorm); v = max over wanted cols
  const float coef = -2.f * sgn;
  int   ccR[16]; float snR[16];
  #pragma unroll
  for (int ci = 0; ci < 4; ++ci)
    #pragma unroll
    for (int rg = 0; rg < 4; ++rg) {
      const int i = wa * 64 + ci * 16 + g * 4 + rg;
      ccR[ci * 4 + rg] = ccS[i];
      snR[ci * 4 + rg] = sgn * nS[i];
    }
  #pragma unroll
  for (int rj = 0; rj < 4; ++rj) {
    const int j  = wb * 64 + rj * 16 + lr;        // block-local row
    const int rc = rcS[j];
    float v = NEG_INF;
    #pragma unroll
    for (int ci = 0; ci < 4; ++ci)
      #pragma unroll
      for (int rg = 0; rg < 4; ++rg) {
        const int idx = ci * 4 + rg;
        const bool same = (rc == ccR[idx]);
        const bool want = z ? !same : same;
        const float q = fmaf(coef, acc[ci][rj][rg], snR[idx]);
        v = fmaxf(v, want ? q : NEG_INF);
      }
    // reduce over the 4 g-groups (lane bits 4,5)
    v = fmaxf(v, __shfl_xor(v, 16));
    v = fmaxf(v, __shfl_xor(v, 32));
    if (g == 0) red[wa][j] = v;
  }
  __syncthreads();
  if (t < 128) {
    const float v = fmaxf(red[0][t], red[1][t]);
    float* __restrict__ outp = z ? minN : maxP;
    // transposed partial layout [row][cb] -> coalesced float4 reads in finalize
    outp[(size_t)(rowbase + t) * nCB + cb] = sgn * v;   // z=1: -max(-x) = min(x)
  }
}

// ---------------- finalize: combine partials, loss, mean ----------------------
__global__ void finalize_kernel(const float* __restrict__ maxP, const float* __restrict__ minN,
                                const float* __restrict__ an, float* out, int N, int nCB) {
  const int r = blockIdx.x * 256 + threadIdx.x;
  const float4* __restrict__ mp = (const float4*)(maxP + (size_t)r * nCB);
  const float4* __restrict__ np = (const float4*)(minN + (size_t)r * nCB);
  float mx = NEG_INF, mn = 3.0e38f;
  for (int i = 0; i < (nCB >> 2); ++i) {
    const float4 a = mp[i];
    mx = fmaxf(mx, fmaxf(fmaxf(a.x, a.y), fmaxf(a.z, a.w)));
    const float4 b = np[i];
    mn = fminf(mn, fminf(fminf(b.x, b.y), fminf(b.z, b.w)));
  }
  const float aa = an[r];
  const float dp = sqrtf(fmaxf(aa + mx, 1e-12f));
  const float dn = sqrtf(fmaxf(aa + mn, 1e-12f));
  float loss = fmaxf(dp - dn + MARGIN, 0.f);
  #pragma unroll
  for (int msk = 1; msk < 64; msk <<= 1) loss += __shfl_xor(loss, msk);
  __shared__ float s[4];
  if ((threadIdx.x & 63) == 0) s[threadIdx.x >> 6] = loss;
  __syncthreads();
  if (threadIdx.x == 0)
    atomicAdd(out, (s[0] + s[1] + s[2] + s[3]) * (1.0f / N));
}

extern "C" void kernel_launch(void* const* d_in, const int* in_sizes, int n_in,
                              void* d_out, int out_size, void* d_ws, size_t ws_size,
                              hipStream_t stream) {
  const float* A  = (const float*)d_in[0];
  const float* P  = (const float*)d_in[1];
  const float* Ng = (const float*)d_in[2];
  const int*   tg = (const int*)d_in[3];
  float* out = (float*)d_out;

  const int N = in_sizes[3];        // 8192
  const int D = in_sizes[0] / N;    // 256
  const int nRB = N / 128, nCB = N / 128;

  char* ws = (char*)d_ws;
  const size_t bf = (size_t)N * D * sizeof(u16);
  u16* Ab = (u16*)ws;
  u16* Pb = (u16*)(ws + bf);
  u16* Nb = (u16*)(ws + 2 * bf);
  char* p = ws + 3 * bf;
  float* an = (float*)p; p += (size_t)N * 4;
  float* pn = (float*)p; p += (size_t)N * 4;
  float* nn = (float*)p; p += (size_t)N * 4;
  int*  cls = (int*)p;   p += (size_t)N * 4;
  float* maxP = (float*)p; p += (size_t)nCB * N * 4;
  float* minN = (float*)p;

  prep_kernel<<<dim3(N / 4, 3), 256, 0, stream>>>(A, P, Ng, tg, Ab, Pb, Nb,
                                                  an, pn, nn, cls, out, D, N);
  triplet_tile_kernel<<<dim3(nCB, nRB, 2), 256, 0, stream>>>(Ab, Pb, Nb, pn, nn, cls,
                                                             maxP, minN, N, D, nCB);
  finalize_kernel<<<N / 256, 256, 0, stream>>>(maxP, minN, an, out, N, nCB);
}

// Round 12
// 149.205 us; speedup vs baseline: 1.6372x; 1.0933x over previous
//
#include <hip/hip_runtime.h>
#include <hip/hip_bf16.h>

typedef unsigned short u16;
typedef __bf16 bf16x8 __attribute__((ext_vector_type(8)));
typedef float f32x4 __attribute__((ext_vector_type(4)));
typedef int   i32x4 __attribute__((ext_vector_type(4)));

#define MARGIN 0.2f
#define NEG_INF -3.0e38f

__device__ __forceinline__ u16 f2bf_rne(float f) {
  unsigned u = __builtin_bit_cast(unsigned, f);
  u += 0x7FFFu + ((u >> 16) & 1u);
  return (u16)(u >> 16);
}

// ---------------- prep: fp32 -> bf16 + row sum-of-squares (+ fused zero/cvt) ---
__global__ void prep_kernel(const float* __restrict__ A, const float* __restrict__ P,
                            const float* __restrict__ Ng, const int* __restrict__ tg,
                            u16* __restrict__ Ab, u16* __restrict__ Pb, u16* __restrict__ Nb,
                            float* __restrict__ an, float* __restrict__ pn, float* __restrict__ nn,
                            int* __restrict__ cls, float* __restrict__ out, int D, int N) {
  if (blockIdx.y == 0) {
    if (blockIdx.x == 0 && threadIdx.x == 0) out[0] = 0.f;
    if ((int)blockIdx.x < (N >> 8)) {
      const int i = blockIdx.x * 256 + threadIdx.x;
      cls[i] = tg[i];
    }
  }
  const int row  = blockIdx.x * 4 + (threadIdx.x >> 6);
  const int lane = threadIdx.x & 63;
  const float* src; u16* dst; float* nrm;
  if (blockIdx.y == 0)      { src = A;  dst = Ab; nrm = an; }
  else if (blockIdx.y == 1) { src = P;  dst = Pb; nrm = pn; }
  else                      { src = Ng; dst = Nb; nrm = nn; }
  float4 v = *(const float4*)(src + (size_t)row * D + lane * 4);
  float ss = v.x * v.x + v.y * v.y + v.z * v.z + v.w * v.w;
  ushort4 o = make_ushort4(f2bf_rne(v.x), f2bf_rne(v.y), f2bf_rne(v.z), f2bf_rne(v.w));
  *(ushort4*)(dst + (size_t)row * D + lane * 4) = o;
  #pragma unroll
  for (int m = 1; m < 64; m <<= 1) ss += __shfl_xor(ss, m);
  if (lane == 0) nrm[row] = ss;
}

// ---------------- main fused kernel: A-in-registers, B-tile sweep -------------
// Each block: 128 A-rows (4 waves x 32 rows, K=256 entirely in VGPRs) sweeps 16
// column-tiles of 64 P/N-cols x K=256. Per cb-tile: ONE stage+drain (no K-loop
// barriers), 32 ds_read_b128 + 64 MFMA per wave, masked-reduce into running
// per-row vmax. z=0 -> row-max vs positives; z=1 -> row-min via -max(-x).
// B-tile rows 512B, XOR swizzle slot^=(row&7) (conflict-free within 8-lane
// groups); realized stage-side by pre-swizzled global source (involution).
__global__ __launch_bounds__(256, 3) void triplet_cb_kernel(
    const u16* __restrict__ Ab, const u16* __restrict__ Pb, const u16* __restrict__ Nb,
    const float* __restrict__ pnorm, const float* __restrict__ nnorm,
    const int* __restrict__ cls,
    float* __restrict__ maxP, float* __restrict__ minN, int N, int D, int ngrp) {
  __shared__ __align__(16) u16  Bs[64 * 256];    // 32 KB, row = 512 B
  __shared__ __align__(16) int   ccL[1024];      // 4 KB: block's col classes
  __shared__ __align__(16) float snL[1024];      // 4 KB: sgn * col norms

  const int grp = blockIdx.x, rg_ = blockIdx.y, z = blockIdx.z;
  const int rowbase = rg_ * 128, colbase0 = grp * 1024;
  const u16*  __restrict__ Bmat = z ? Nb : Pb;
  const float* __restrict__ cn  = z ? nnorm : pnorm;
  const float sgn  = z ? -1.f : 1.f;
  const float coef = -2.f * sgn;

  const int t = threadIdx.x, l = t & 63, w = t >> 6;
  const int lr = l & 15, g = (l >> 4) & 3;

  // stage classes + signed norms for the block's 1024 columns
  #pragma unroll
  for (int i = 0; i < 4; ++i) {
    const int c = i * 256 + t;
    ccL[c] = cls[colbase0 + c];
    snL[c] = sgn * cn[colbase0 + c];
  }

  // A-fragments in registers: af[rj][kk] = A[arow0 + rj*16][kk*32 + g*8 ..+7]
  // (B-operand layout: out-col = lane&15, k = g*8 + j)  -- 64 VGPRs
  const int arow0 = rowbase + w * 32 + lr;
  bf16x8 af[2][8];
  #pragma unroll
  for (int rj = 0; rj < 2; ++rj)
    #pragma unroll
    for (int kk = 0; kk < 8; ++kk)
      af[rj][kk] = *(const bf16x8*)(Ab + (size_t)(arow0 + rj * 16) * D + kk * 32 + g * 8);

  int rc[2];
  rc[0] = cls[arow0];
  rc[1] = cls[arow0 + 16];

  float vmax[2] = {NEG_INF, NEG_INF};

  const int rowpar = w * 2 + (l >> 5);   // staging row bits: row = c*8 + rowpar
  const int slot0  = l & 31;

  for (int cb = 0; cb < 16; ++cb) {
    const int colbase = colbase0 + cb * 64;
    __syncthreads();                      // prior tile fully consumed
    // stage B-tile (64 cols x 256 K): 8 x 1 KB per wave, linear LDS dest,
    // pre-swizzled global source
    #pragma unroll
    for (int c = 0; c < 8; ++c) {
      const int row  = c * 8 + rowpar;
      const int slot = slot0 ^ (row & 7);
      const u16* gp = Bmat + (size_t)(colbase + row) * D + slot * 8;
      u16* lp = Bs + c * 2048 + w * 512;  // bytes: c*4096 + w*1024 (+lane*16 by HW)
      __builtin_amdgcn_global_load_lds((const __attribute__((address_space(1))) void*)gp,
                                       (__attribute__((address_space(3))) void*)lp,
                                       16, 0, 0);
    }
    __syncthreads();                      // drains vmcnt -> tile visible

    // full-K compute, no barriers: acc[ci][rj] over kk
    f32x4 acc[4][2];
    const f32x4 zero = (f32x4){0.f, 0.f, 0.f, 0.f};
    #pragma unroll
    for (int kk = 0; kk < 8; ++kk) {
      bf16x8 bf[4];
      #pragma unroll
      for (int ci = 0; ci < 4; ++ci) {
        const int p    = ci * 16 + lr;
        const int addr = p * 512 + (((kk * 4 + g) ^ (l & 7)) * 16);
        bf[ci] = *(const bf16x8*)((const char*)Bs + addr);
      }
      #pragma unroll
      for (int ci = 0; ci < 4; ++ci)
        #pragma unroll
        for (int rj = 0; rj < 2; ++rj)
          acc[ci][rj] = __builtin_amdgcn_mfma_f32_16x16x32_bf16(
              bf[ci], af[rj][kk], kk == 0 ? zero : acc[ci][rj], 0, 0, 0);
    }

    // masked reduce into running vmax (cols in regs: out-col = ci*16 + g*4 + rg)
    #pragma unroll
    for (int ci = 0; ci < 4; ++ci) {
      const int cl = cb * 64 + ci * 16 + g * 4;
      const i32x4 cc4 = *(const i32x4*)&ccL[cl];
      const f32x4 sn4 = *(const f32x4*)&snL[cl];
      #pragma unroll
      for (int rg = 0; rg < 4; ++rg)
        #pragma unroll
        for (int rj = 0; rj < 2; ++rj) {
          const float q   = fmaf(coef, acc[ci][rj][rg], sn4[rg]);
          const bool same = (rc[rj] == cc4[rg]);
          const bool want = z ? !same : same;
          vmax[rj] = fmaxf(vmax[rj], want ? q : NEG_INF);
        }
    }
  }

  // reduce over the 4 g-groups (lane bits 4,5); rows live in lane&15
  #pragma unroll
  for (int rj = 0; rj < 2; ++rj) {
    float v = vmax[rj];
    v = fmaxf(v, __shfl_xor(v, 16));
    v = fmaxf(v, __shfl_xor(v, 32));
    if ((l >> 4) == 0) {
      const int row = arow0 + rj * 16;
      float* __restrict__ outp = z ? minN : maxP;
      outp[(size_t)row * ngrp + grp] = sgn * v;   // z=1: -max(-x) = min(x)
    }
  }
}

// ---------------- finalize: combine 8 group-partials, loss, mean --------------
__global__ void finalize_kernel(const float* __restrict__ maxP, const float* __restrict__ minN,
                                const float* __restrict__ an, float* out, int N, int ngrp) {
  const int r = blockIdx.x * 256 + threadIdx.x;
  float mx = NEG_INF, mn = 3.0e38f;
  for (int i = 0; i < ngrp; ++i) {
    mx = fmaxf(mx, maxP[(size_t)r * ngrp + i]);
    mn = fminf(mn, minN[(size_t)r * ngrp + i]);
  }
  const float aa = an[r];
  const float dp = sqrtf(fmaxf(aa + mx, 1e-12f));
  const float dn = sqrtf(fmaxf(aa + mn, 1e-12f));
  float loss = fmaxf(dp - dn + MARGIN, 0.f);
  #pragma unroll
  for (int msk = 1; msk < 64; msk <<= 1) loss += __shfl_xor(loss, msk);
  __shared__ float s[4];
  if ((threadIdx.x & 63) == 0) s[threadIdx.x >> 6] = loss;
  __syncthreads();
  if (threadIdx.x == 0)
    atomicAdd(out, (s[0] + s[1] + s[2] + s[3]) * (1.0f / N));
}

extern "C" void kernel_launch(void* const* d_in, const int* in_sizes, int n_in,
                              void* d_out, int out_size, void* d_ws, size_t ws_size,
                              hipStream_t stream) {
  const float* A  = (const float*)d_in[0];
  const float* P  = (const float*)d_in[1];
  const float* Ng = (const float*)d_in[2];
  const int*   tg = (const int*)d_in[3];
  float* out = (float*)d_out;

  const int N = in_sizes[3];        // 8192
  const int D = in_sizes[0] / N;    // 256
  const int ngrp = N / 1024;        // 8 column groups (1024 cols each)

  char* ws = (char*)d_ws;
  const size_t bf = (size_t)N * D * sizeof(u16);
  u16* Ab = (u16*)ws;
  u16* Pb = (u16*)(ws + bf);
  u16* Nb = (u16*)(ws + 2 * bf);
  char* p = ws + 3 * bf;
  float* an = (float*)p; p += (size_t)N * 4;
  float* pn = (float*)p; p += (size_t)N * 4;
  float* nn = (float*)p; p += (size_t)N * 4;
  int*  cls = (int*)p;   p += (size_t)N * 4;
  float* maxP = (float*)p; p += (size_t)N * ngrp * 4;
  float* minN = (float*)p;

  prep_kernel<<<dim3(N / 4, 3), 256, 0, stream>>>(A, P, Ng, tg, Ab, Pb, Nb,
                                                  an, pn, nn, cls, out, D, N);
  triplet_cb_kernel<<<dim3(ngrp, N / 128, 2), 256, 0, stream>>>(Ab, Pb, Nb, pn, nn, cls,
                                                                maxP, minN, N, D, ngrp);
  finalize_kernel<<<N / 256, 256, 0, stream>>>(maxP, minN, an, out, N, ngrp);
}